// Round 4
// baseline (7773.926 us; speedup 1.0000x reference)
//
#include <hip/hip_runtime.h>

typedef short bf16x8 __attribute__((ext_vector_type(8)));   // 8 bf16 in 4 VGPRs
typedef float f32x4  __attribute__((ext_vector_type(4)));
typedef int   i32x4  __attribute__((ext_vector_type(4)));

#define DEVINL __device__ __forceinline__

// ---------------------------------------------------------------------------
// Problem: B=256, T=128, V=10000, E=256, U=1024, 4U=4096, O=1024
// fixed ws ~85 MB + tc*5.25 MB
// ---------------------------------------------------------------------------
static constexpr size_t SZ_WIM  = 4096ull * 512 * 2;   // W img  [4096][hi256|lo256]
static constexpr size_t SZ_FCW  = 1024ull * 2048 * 2;  // fc img [1024][hi1024|lo1024]
static constexpr size_t SZ_UIM  = 8388608;             // U i8 frag img, 2 planes
static constexpr size_t SZ_HH   = 129ull * 524288;     // h history [129 t][2 pl][256][1024] i8
static constexpr size_t SZ_CB   = 1048576;             // c state [256][1024] f32
static constexpr size_t SZ_LEN  = 4096;
static constexpr size_t SZ_DIAG = 512;                 // prog[0..31] + bar[mb] at 32+16*mb

DEVINL unsigned short bf16rn(float x){
  unsigned u = __float_as_uint(x);
  unsigned r = (u + 0x7fffu + ((u >> 16) & 1u)) >> 16;
  return (unsigned short)r;
}
DEVINL unsigned short bf16lo(float x){
  unsigned ub = __float_as_uint(x);
  return bf16rn(x - __uint_as_float(ub & 0xffff0000u));
}
DEVINL float sigm(float x){ return 1.f / (1.f + __expf(-x)); }
DEVINL float tanhfast(float x){
  float xc = fminf(15.f, fmaxf(-15.f, x));
  float e = __expf(2.f * xc);
  return (e - 1.f) / (e + 1.f);
}

// ---------------------------------------------------------------------------
__global__ void __launch_bounds__(256) probe_fill(float* __restrict__ out, int n, float v)
{
  int i = blockIdx.x * 256 + threadIdx.x;
  if (i < n) out[i] = (i == 0) ? v : 0.f;
}

// diag: if a stage marker is missing, flood out[0..1023] with 100+stage
__global__ void __launch_bounds__(64) diag_check(const int* __restrict__ prog,
                                                 float* __restrict__ out)
{
  if (threadIdx.x == 0){
    int miss = 0;
    for (int i = 7; i >= 1; i--) if (prog[i] == 0) miss = i;
    if (miss){
      for (int k = 0; k < 1024; k++) out[k] = 100.0f + (float)miss;
    }
  }
}

// ---------------------------------------------------------------------------
__global__ void __launch_bounds__(128) len_kernel(const int* __restrict__ seq,
                                                  int* __restrict__ len,
                                                  int* __restrict__ prog)
{
  int b = blockIdx.x, t = threadIdx.x;
  if (b == 0 && t == 0) prog[1] = 1;
  int pred = (seq[b * 128 + t] != 0) ? 1 : 0;
  unsigned long long m = __ballot(pred);
  __shared__ int cnt[2];
  if ((t & 63) == 0) cnt[t >> 6] = __popcll(m);
  __syncthreads();
  if (t == 0) len[b] = cnt[0] + cnt[1];
}

// ---------------------------------------------------------------------------
// transpose f32 [Ksrc][N] -> bf16 image [N][2*Ksrc] = [hi | lo]
// ---------------------------------------------------------------------------
__global__ void __launch_bounds__(256) prep_split_img(
    const float* __restrict__ S, unsigned short* __restrict__ img, int N, int Ksrc,
    int* __restrict__ prog, int stage)
{
  __shared__ float tile[64][65];
  const int nt = N >> 6;
  const int bn = blockIdx.x % nt, bk = blockIdx.x / nt;
  const int tid = threadIdx.x;
  if (blockIdx.x == 0 && tid == 0) prog[stage] = 1;
  {
    const int kk = tid >> 6, n = tid & 63;
#pragma unroll 4
    for (int i = 0; i < 16; i++){
      int k = i * 4 + kk;
      tile[k][n] = S[(size_t)((bk << 6) + k) * N + (bn << 6) + n];
    }
  }
  __syncthreads();
  {
    const int n4 = tid >> 6, k = tid & 63;
#pragma unroll 4
    for (int i = 0; i < 16; i++){
      int n = i * 4 + n4;
      float v = tile[k][n];
      size_t rowoff = (size_t)((bn << 6) + n) * (2 * Ksrc) + (bk << 6) + k;
      img[rowoff] = (unsigned short)(__float_as_uint(v) >> 16);
      img[rowoff + Ksrc] = bf16lo(v);
    }
  }
}

// ---------------------------------------------------------------------------
// U (f32 [1024][4096]) -> i8 fragment image, 2 planes (hi,lo of 16-bit *2^17)
// ---------------------------------------------------------------------------
__global__ void __launch_bounds__(256) prep_uimg(const float* __restrict__ U,
                                                 signed char* __restrict__ img,
                                                 int* __restrict__ prog)
{
  const int bid = blockIdx.x;
  const int nb = bid >> 2, nt4 = bid & 3;
  const int tid = threadIdx.x;
  if (bid == 0 && tid == 0) prog[4] = 1;
  __shared__ signed char lc[16384], ldq[16384];  // [k 1024][16 cols]
  const int colbase = nt4 * 1024 + (nb << 4);
  const int kk = tid >> 4, cc = tid & 15;
#pragma unroll 4
  for (int it = 0; it < 64; it++){
    int k = it * 16 + kk;
    float v = U[(size_t)k * 4096 + colbase + cc];
    int q = (int)rintf(v * 131072.f);            // U * 2^17
    q = q > 32639 ? 32639 : (q < -32639 ? -32639 : q);
    int a = (q + 128) >> 8;
    int d = q - (a << 8);
    lc[(k << 4) + cc]  = (signed char)a;
    ldq[(k << 4) + cc] = (signed char)d;
  }
  __syncthreads();
#pragma unroll
  for (int rep = 0; rep < 4; rep++){
    int idx = rep * 256 + tid;                   // 0..1023
    int kt = idx >> 6, lane = idx & 63;
    int n = lane & 15, quad = lane >> 4;
    union { signed char b[16]; i32x4 v; } cb_, db_;
#pragma unroll
    for (int j = 0; j < 16; j++){
      int k = (kt << 6) + (quad << 4) + j;
      cb_.b[j] = lc[(k << 4) + n];
      db_.b[j] = ldq[(k << 4) + n];
    }
    size_t base = (size_t)((((nb << 2) + nt4) * 16 + kt) * 2) * 1024;
    *(i32x4*)(img + base + (size_t)lane * 16)        = cb_.v;
    *(i32x4*)(img + base + 1024 + (size_t)lane * 16) = db_.v;
  }
}

// ---------------------------------------------------------------------------
// gates GEMM: xg[256*tc][4096] = token-gathered emb x Wimg + bias (3-product).
// ---------------------------------------------------------------------------
__global__ void __launch_bounds__(256) gemm_gates(
    const float* __restrict__ emb, const unsigned short* __restrict__ Bimg,
    const float* __restrict__ bias, float* __restrict__ D,
    const int* __restrict__ seq, int c0, int tcsh, int* __restrict__ prog)
{
  __shared__ __align__(16) char lds[16384];   // A 8KB | B 8KB
  __shared__ int stok[128];
  const int tid = threadIdx.x, lane = tid & 63, wv = tid >> 6;
  const int quad = lane >> 4, nlo = lane & 15;
  const int wm = wv & 1, wn = wv >> 1;
  const int rowbase = (blockIdx.x >> 5) << 7;   // 32 col-tiles
  const int colbase = (blockIdx.x & 31) << 7;
  const int tcm1 = (1 << tcsh) - 1;
  if (blockIdx.x == 0 && tid == 0) prog[5] = 1;
  if (tid < 128){
    int r = rowbase + tid;
    stok[tid] = seq[((r >> tcsh) << 7) + c0 + (r & tcm1)];
  }
  __syncthreads();

  f32x4 acc[4][4];
#pragma unroll
  for (int i = 0; i < 4; i++)
#pragma unroll
    for (int j = 0; j < 4; j++) acc[i][j] = (f32x4){0.f, 0.f, 0.f, 0.f};

  float4 va[2][2]; int4 vb[2];
  auto loadAB = [&](int c){
    int k0 = c * 32;
    int seg = (k0 >= 512) ? 2 : (k0 >= 256 ? 1 : 0);
    int acol = k0 - seg * 256;
    int boff = (seg == 2 ? 256 : 0) + acol;
#pragma unroll
    for (int p = 0; p < 2; p++){
      int gidx = p * 256 + tid;
      int row = gidx >> 2, sg = gidx & 3;
      const float* ap = emb + (size_t)stok[row] * 256 + acol + sg * 8;
      va[p][0] = *(const float4*)ap;
      va[p][1] = *(const float4*)(ap + 4);
      vb[p] = *(const int4*)(Bimg + (size_t)(colbase + row) * 512 + boff + sg * 8);
    }
  };
  auto writeAB = [&](int c){
    int k0 = c * 32;
    int seg = (k0 >= 512) ? 2 : (k0 >= 256 ? 1 : 0);
#pragma unroll
    for (int p = 0; p < 2; p++){
      int gidx = p * 256 + tid;
      int row = gidx >> 2, sg = gidx & 3;
      float vv[8] = {va[p][0].x, va[p][0].y, va[p][0].z, va[p][0].w,
                     va[p][1].x, va[p][1].y, va[p][1].z, va[p][1].w};
      union { unsigned short s[8]; int4 q; } pk;
      if (seg == 1){
#pragma unroll
        for (int j = 0; j < 8; j++) pk.s[j] = bf16lo(vv[j]);
      } else {
#pragma unroll
        for (int j = 0; j < 8; j++) pk.s[j] = (unsigned short)(__float_as_uint(vv[j]) >> 16);
      }
      int sw = (sg ^ ((row >> 1) & 3)) << 4;
      *(int4*)(&lds[row * 64 + sw]) = pk.q;
      *(int4*)(&lds[8192 + row * 64 + sw]) = vb[p];
    }
  };

  loadAB(0);
#pragma unroll 2
  for (int c = 0; c < 24; c++){
    __syncthreads();
    writeAB(c);
    __syncthreads();
    if (c + 1 < 24) loadAB(c + 1);
    bf16x8 af[4], bfr[4];
#pragma unroll
    for (int mt = 0; mt < 4; mt++){
      int r = wm * 64 + mt * 16 + nlo;
      af[mt] = *(const bf16x8*)(&lds[r * 64 + ((quad ^ ((r >> 1) & 3)) << 4)]);
    }
#pragma unroll
    for (int nt = 0; nt < 4; nt++){
      int r = wn * 64 + nt * 16 + nlo;
      bfr[nt] = *(const bf16x8*)(&lds[8192 + r * 64 + ((quad ^ ((r >> 1) & 3)) << 4)]);
    }
#pragma unroll
    for (int mt = 0; mt < 4; mt++)
#pragma unroll
      for (int nt = 0; nt < 4; nt++)
        acc[mt][nt] = __builtin_amdgcn_mfma_f32_16x16x32_bf16(af[mt], bfr[nt], acc[mt][nt], 0, 0, 0);
  }

  float bs[4];
#pragma unroll
  for (int nt = 0; nt < 4; nt++) bs[nt] = bias[colbase + wn * 64 + nt * 16 + nlo];
#pragma unroll
  for (int mt = 0; mt < 4; mt++)
#pragma unroll
    for (int nt = 0; nt < 4; nt++){
      int col = colbase + wn * 64 + nt * 16 + nlo;
#pragma unroll
      for (int r = 0; r < 4; r++){
        int row = rowbase + wm * 64 + mt * 16 + quad * 4 + r;
        D[(size_t)row * 4096 + col] = acc[mt][nt][r] + bs[nt];
      }
    }
}

// ---------------------------------------------------------------------------
// output GEMM: out[b*128+c0+s][1024] = ohol x fcw + fcb (3-product, K'=3072)
// ---------------------------------------------------------------------------
__global__ void __launch_bounds__(256) gemm_out(
    const unsigned short* __restrict__ ohol, const unsigned short* __restrict__ Bimg,
    const float* __restrict__ bias, float* __restrict__ D,
    int c0, int tcsh, int* __restrict__ prog)
{
  __shared__ __align__(16) char lds[16384];
  const int tid = threadIdx.x, lane = tid & 63, wv = tid >> 6;
  const int quad = lane >> 4, nlo = lane & 15;
  const int wm = wv & 1, wn = wv >> 1;
  const int rowbase = (blockIdx.x >> 3) << 7;   // 8 col-tiles
  const int colbase = (blockIdx.x & 7) << 7;
  const int tcm1 = (1 << tcsh) - 1;
  if (blockIdx.x == 0 && tid == 0) prog[7] = 1;

  f32x4 acc[4][4];
#pragma unroll
  for (int i = 0; i < 4; i++)
#pragma unroll
    for (int j = 0; j < 4; j++) acc[i][j] = (f32x4){0.f, 0.f, 0.f, 0.f};

  int4 va[2], vb[2];
  auto loadAB = [&](int c){
    int k0 = c * 32;
    int seg = (k0 >= 2048) ? 2 : (k0 >= 1024 ? 1 : 0);
    int acol = k0 - seg * 1024;
    int aoff = (seg == 1 ? 1024 : 0) + acol;
    int boff = (seg == 2 ? 1024 : 0) + acol;
#pragma unroll
    for (int p = 0; p < 2; p++){
      int gidx = p * 256 + tid;
      int row = gidx >> 2, sg = gidx & 3;
      va[p] = *(const int4*)(ohol + (size_t)(rowbase + row) * 2048 + aoff + sg * 8);
      vb[p] = *(const int4*)(Bimg + (size_t)(colbase + row) * 2048 + boff + sg * 8);
    }
  };
  auto writeAB = [&](){
#pragma unroll
    for (int p = 0; p < 2; p++){
      int gidx = p * 256 + tid;
      int row = gidx >> 2, sg = gidx & 3;
      int sw = (sg ^ ((row >> 1) & 3)) << 4;
      *(int4*)(&lds[row * 64 + sw]) = va[p];
      *(int4*)(&lds[8192 + row * 64 + sw]) = vb[p];
    }
  };

  loadAB(0);
#pragma unroll 2
  for (int c = 0; c < 96; c++){
    __syncthreads();
    writeAB();
    __syncthreads();
    if (c + 1 < 96) loadAB(c + 1);
    bf16x8 af[4], bfr[4];
#pragma unroll
    for (int mt = 0; mt < 4; mt++){
      int r = wm * 64 + mt * 16 + nlo;
      af[mt] = *(const bf16x8*)(&lds[r * 64 + ((quad ^ ((r >> 1) & 3)) << 4)]);
    }
#pragma unroll
    for (int nt = 0; nt < 4; nt++){
      int r = wn * 64 + nt * 16 + nlo;
      bfr[nt] = *(const bf16x8*)(&lds[8192 + r * 64 + ((quad ^ ((r >> 1) & 3)) << 4)]);
    }
#pragma unroll
    for (int mt = 0; mt < 4; mt++)
#pragma unroll
      for (int nt = 0; nt < 4; nt++)
        acc[mt][nt] = __builtin_amdgcn_mfma_f32_16x16x32_bf16(af[mt], bfr[nt], acc[mt][nt], 0, 0, 0);
  }

  float bs[4];
#pragma unroll
  for (int nt = 0; nt < 4; nt++) bs[nt] = bias[colbase + wn * 64 + nt * 16 + nlo];
#pragma unroll
  for (int mt = 0; mt < 4; mt++)
#pragma unroll
    for (int nt = 0; nt < 4; nt++){
      int col = colbase + wn * 64 + nt * 16 + nlo;
#pragma unroll
      for (int r = 0; r < 4; r++){
        int row = rowbase + wm * 64 + mt * 16 + quad * 4 + r;
        int drow = ((row >> tcsh) << 7) + c0 + (row & tcm1);
        D[(size_t)drow * 1024 + col] = acc[mt][nt][r] + bs[nt];
      }
    }
}

// ---------------------------------------------------------------------------
// per-mb-group barrier (16 WGs), monotonic counter.
// Writer-release / address-freshness protocol (PROVEN in round 3):
//   - h(t+1) stores are PLAIN stores (dirty in writer's XCD L2).
//   - arrival = RELEASE agent fetch_add (vmcnt drain + buffer_wbl2 sc1 with
//     ack before the flag is visible -> data at MALL before flag).
//   - spin with RELAXED loads (no cache ops per poll).
//   - NO reader-side invalidate: slot t+1 addresses are launch-fresh, so no
//     L1/L2 can hold a stale copy (dispatch acquire invalidated caches).
//   - workgroup acquire fence = compiler-only ordering below the spin.
// Round-4 change: 16 arrivals/group (was 64) -> 4x less RMW serialization
// and 4x fewer wbl2 ops chip-wide per step.
// ---------------------------------------------------------------------------
DEVINL void mbbar(int* bar, int t, int tid){
  __syncthreads();   // all threads' stores issued (per-wave vmcnt drained)
  if (tid == 0){
    __hip_atomic_fetch_add(bar, 1, __ATOMIC_RELEASE, __HIP_MEMORY_SCOPE_AGENT);
    const int target = 16 * (t + 1);
    while (__hip_atomic_load(bar, __ATOMIC_RELAXED, __HIP_MEMORY_SCOPE_AGENT) < target)
      __builtin_amdgcn_s_sleep(1);
    __builtin_amdgcn_fence(__ATOMIC_ACQUIRE, "workgroup");  // compiler ordering only
  }
  __syncthreads();
}

// ---------------------------------------------------------------------------
// persistent LSTM recurrence, tc steps/launch.  64 WGs x 1024 thr = 4 mb x 16 wgn.
// Each WG: 64 u-cols (vs 16 before) -> 4x less h all-gather traffic, 16 waves/CU
// (4/SIMD) for latency hiding, 16-arrival barrier.
// Wave wv (16): wm=wv&1 (M-half of 64 b-rows), gp=(wv>>1)&1 (gate pair),
// un=wv>>2 (16-col u-block within WG's 64).  Per-wave structure (U frags,
// MFMA counts, LDS swizzles) identical to the proven 256-thread version.
// h,U 2-plane i8 fixed point (h*32512 = 256a+d; U*2^17 = 256c+e); exact i32.
// h state streams through hh[t] (never-reused addresses, see mbbar comment).
// ---------------------------------------------------------------------------
__global__ void __launch_bounds__(1024, 4) lstm_rec(
    const float* __restrict__ xg,        // [256*tc][4096] f32, row = b*tc+s
    const signed char* __restrict__ uimg,
    const int* __restrict__ len,
    signed char* __restrict__ hh,        // [129 t][2 pl][256][1024] i8 history
    float* __restrict__ cbuf,            // [256][1024] f32
    unsigned short* __restrict__ ohol,   // [256*tc][hi1024|lo1024]
    int* __restrict__ barbase,           // bar[mb] at barbase + mb*16
    int* __restrict__ prog,
    int c0, int tcsh)
{
  // LDS: [0,16384) h tile (2 pl x 64 r x 128B, XOR swizzle);
  //      [16384, 16384+32*266*4) z f32 [32 rows][266] (one M-half per phase)
  __shared__ __align__(16) char lds[16384 + 32 * 266 * 4];
  float* zb = (float*)(lds + 16384);
  const int tc = 1 << tcsh;
  const int wg = blockIdx.x, mb = wg >> 4, wgn = wg & 15;
  const int tid = threadIdx.x, lane = tid & 63, wv = tid >> 6;   // wv 0..15
  const int quad = lane >> 4, nlo = lane & 15;
  const int wm = wv & 1, gp = (wv >> 1) & 1, un = wv >> 2;
  int* bar = barbase + (mb << 4);
  if (wg == 0 && tid == 0) prog[6] = 1;

  // ---- U fragments -> registers (per-wave slice identical to old kernel) ----
  // col(gate j of pair, u-block un): nb_eff = wgn*4 + un; gate = gp*2 + j
  i32x4 Bf[2][16][2];
#pragma unroll
  for (int j = 0; j < 2; j++)
#pragma unroll
    for (int kt = 0; kt < 16; kt++)
#pragma unroll
      for (int pl = 0; pl < 2; pl++){
        size_t off = (size_t)((((((wgn << 2) + un) << 2) + (gp * 2 + j)) * 16 + kt) * 2 + pl);
        off = (off * 64 + lane) << 4;
        Bf[j][kt][pl] = *(const i32x4*)(uimg + off);
      }

  // ---- per-thread state: 4 b-rows x 1 u-col ----
  // rows (local): k=0,1 -> rr*2+{0,1};  k=2,3 -> 32+rr*2+{0,1};  rr = wv
  const int uu = tid & 63, rr = wv;
  const int ucol = (wgn << 6) + uu;
  float cst[4], hst[4];
  int lenr[4];
#pragma unroll
  for (int k = 0; k < 4; k++){
    int bglob = (mb << 6) + ((k >> 1) << 5) + (rr << 1) + (k & 1);
    lenr[k] = len[bglob];
    cst[k] = cbuf[(size_t)bglob * 1024 + ucol];
    int a  = hh[((size_t)c0 * 512 + 0 * 256 + bglob) * 1024 + ucol];
    int b_ = hh[((size_t)c0 * 512 + 1 * 256 + bglob) * 1024 + ucol];
    hst[k] = (float)(a * 256 + b_) * (1.0f / 32512.0f);
  }

  // xg for the elementwise: 16 f32/thread, prefetched at step top so the whole
  // GEMM covers the MALL latency (xg LDS staging removed entirely).
  float xgr[4][4];   // [k][gate]
  auto load_x = [&](int s){
#pragma unroll
    for (int k = 0; k < 4; k++){
      int bglob = (mb << 6) + ((k >> 1) << 5) + (rr << 1) + (k & 1);
      const float* p = xg + (size_t)(((size_t)bglob << tcsh) + s) * 4096 + ucol;
#pragma unroll
      for (int g = 0; g < 4; g++) xgr[k][g] = p[(size_t)g << 10];
    }
  };

#pragma unroll 1
  for (int s = 0; s < tc; s++){
    const int t = c0 + s;
    const signed char* hsrc = hh + ((size_t)t * 512 + (size_t)(mb << 6)) * 1024;

    load_x(s);

    i32x4 accH[2][2], accM[2][2], accL[2][2];
#pragma unroll
    for (int m = 0; m < 2; m++)
#pragma unroll
      for (int j = 0; j < 2; j++){
        accH[m][j] = (i32x4){0,0,0,0};
        accM[m][j] = (i32x4){0,0,0,0};
        accL[m][j] = (i32x4){0,0,0,0};
      }

    // h staging: 1024 threads cover 16 KB per c-iter, 1 int4 each
    const int hg = tid & 7, hr = (tid >> 3) & 63, hpl = tid >> 9;
    int4 hreg;
    auto load_h = [&](int c){
      hreg = *(const int4*)(hsrc + ((size_t)(hpl * 256 + hr)) * 1024 + c * 128 + hg * 16);
    };
    auto write_h = [&](){
      *(int4*)(&lds[hpl * 8192 + hr * 128 + ((hg ^ (hr & 7)) << 4)]) = hreg;
    };

    load_h(0);

#pragma unroll 1
    for (int c = 0; c < 8; c++){
      __syncthreads();
      write_h();
      __syncthreads();
      if (c < 7) load_h(c + 1);
#pragma unroll
      for (int kt2 = 0; kt2 < 2; kt2++){
        int kt = c * 2 + kt2;
        i32x4 Af[2][2];
#pragma unroll
        for (int m = 0; m < 2; m++)
#pragma unroll
          for (int pl = 0; pl < 2; pl++){
            int hrow = (wm << 5) + (m << 4) + nlo;
            int sgl = ((kt2 << 2) + quad) ^ (hrow & 7);
            Af[m][pl] = *(const i32x4*)(&lds[pl * 8192 + hrow * 128 + (sgl << 4)]);
          }
#pragma unroll
        for (int m = 0; m < 2; m++)
#pragma unroll
          for (int j = 0; j < 2; j++){
            accH[m][j] = __builtin_amdgcn_mfma_i32_16x16x64_i8(Af[m][0], Bf[j][kt][0], accH[m][j], 0, 0, 0);
            accM[m][j] = __builtin_amdgcn_mfma_i32_16x16x64_i8(Af[m][0], Bf[j][kt][1], accM[m][j], 0, 0, 0);
            accM[m][j] = __builtin_amdgcn_mfma_i32_16x16x64_i8(Af[m][1], Bf[j][kt][0], accM[m][j], 0, 0, 0);
            accL[m][j] = __builtin_amdgcn_mfma_i32_16x16x64_i8(Af[m][1], Bf[j][kt][1], accL[m][j], 0, 0, 0);
          }
      }
    }

    // ---- two M-half phases: z -> LDS -> elementwise ----
    const float cH = 1.0f / 65024.0f;
    const float cM = 1.0f / 16646144.0f;
    const float cL = 1.0f / 4261412864.0f;
#pragma unroll
    for (int ph = 0; ph < 2; ph++){
      __syncthreads();   // z buffer free (prev phase/step consumed)
      if (wm == ph){
#pragma unroll
        for (int m = 0; m < 2; m++)
#pragma unroll
          for (int j = 0; j < 2; j++){
            int colb = ((gp * 2 + j) << 6) + (un << 4) + nlo;
#pragma unroll
            for (int r = 0; r < 4; r++){
              float z = (float)accH[m][j][r] * cH
                      + (float)accM[m][j][r] * cM
                      + (float)accL[m][j][r] * cL;
              int rowl = (m << 4) + (quad << 2) + r;
              zb[rowl * 266 + colb] = z;
            }
          }
      }
      __syncthreads();
      // elementwise: all 16 waves, wave rr handles rows {rr*2, rr*2+1}
#pragma unroll
      for (int p = 0; p < 2; p++){
        int k = (ph << 1) + p;
        int rowl = (rr << 1) + p;
        int bglob = (mb << 6) + (ph << 5) + rowl;
        float zi = zb[rowl * 266 +   0 + uu] + xgr[k][0];
        float zf = zb[rowl * 266 +  64 + uu] + xgr[k][1];
        float zg = zb[rowl * 266 + 128 + uu] + xgr[k][2];
        float zo = zb[rowl * 266 + 192 + uu] + xgr[k][3];
        float iv = sigm(zi), fv = sigm(zf), ov = sigm(zo), gv = tanhfast(zg);
        float cn = fv * cst[k] + iv * gv;
        float hn = ov * tanhfast(cn);
        bool vld = (t < lenr[k]);
        cst[k] = vld ? cn : cst[k];
        hst[k] = vld ? hn : hst[k];
        float ho = vld ? hn : 0.f;
        size_t orow = ((size_t)bglob << tcsh) + s;
        ohol[orow * 2048 + ucol]        = (unsigned short)(__float_as_uint(ho) >> 16);
        ohol[orow * 2048 + 1024 + ucol] = bf16lo(ho);
        int H = (int)rintf(hst[k] * 32512.f);
        H = H > 32512 ? 32512 : (H < -32512 ? -32512 : H);
        int a = (H + 128) >> 8;
        int b_ = H - (a << 8);
        // PLAIN stores to the FRESH slot t+1; made remote-visible by mbbar's
        // RELEASE fetch_add (wbl2 with ack) before the flag is seen.
        hh[((size_t)(t + 1) * 512 + 0 * 256 + bglob) * 1024 + ucol] = (signed char)a;
        hh[((size_t)(t + 1) * 512 + 1 * 256 + bglob) * 1024 + ucol] = (signed char)b_;
      }
    }
    mbbar(bar, t, tid);
  }

#pragma unroll
  for (int k = 0; k < 4; k++){
    int bglob = (mb << 6) + ((k >> 1) << 5) + (rr << 1) + (k & 1);
    cbuf[(size_t)bglob * 1024 + ucol] = cst[k];
  }
}

// ---------------------------------------------------------------------------
extern "C" void kernel_launch(void* const* d_in, const int* in_sizes, int n_in,
                              void* d_out, int out_size, void* d_ws, size_t ws_size,
                              hipStream_t stream)
{
  const int*   seq = (const int*)  d_in[0];
  const float* emb = (const float*)d_in[1];
  const float* Wm  = (const float*)d_in[2];
  const float* Um  = (const float*)d_in[3];
  const float* bv  = (const float*)d_in[4];
  const float* fcW = (const float*)d_in[5];
  const float* fcb = (const float*)d_in[6];
  float* out = (float*)d_out;
  char* ws = (char*)d_ws;

  // marker: survives iff no kernel/memset below ever touches d_out
  hipMemsetAsync(d_out, 0x42, 256, stream);   // 64 floats = 48.566

  size_t off = 0;
  unsigned short* wim = (unsigned short*)(ws + off); off += SZ_WIM;
  unsigned short* fcw = (unsigned short*)(ws + off); off += SZ_FCW;
  signed char*    uim = (signed char*)(ws + off);    off += SZ_UIM;
  signed char*    hh  = (signed char*)(ws + off);    off += SZ_HH;
  float*          cb  = (float*)(ws + off);          off += SZ_CB;
  int*            len = (int*)(ws + off);            off += SZ_LEN;
  int*            diag= (int*)(ws + off);            off += SZ_DIAG;
  const size_t fixed = off;

  int tcsh = -1;
  for (int s = 5; s >= 0; s--)
    if (ws && fixed + (5242880ull << s) <= ws_size){ tcsh = s; break; }

  if (tcsh < 0){
    probe_fill<<<(out_size + 255) / 256, 256, 0, stream>>>(
        out, out_size, 1000.0f + (float)(ws_size >> 20));
    return;
  }
  const int tc = 1 << tcsh;

  float*          xgc  = (float*)(ws + fixed);
  unsigned short* ohol = (unsigned short*)(ws + fixed + (size_t)tc * 4194304);

  hipMemsetAsync(diag, 0, SZ_DIAG, stream);   // prog + per-mb barrier counters
  hipMemsetAsync(hh, 0, 524288, stream);      // h history slot 0 = 0
  hipMemsetAsync(cb, 0, SZ_CB, stream);       // c state = 0

  int* prog = diag;
  int* barbase = diag + 32;

  len_kernel<<<256, 128, 0, stream>>>(seq, len, prog);
  prep_split_img<<<256, 256, 0, stream>>>(Wm, wim, 4096, 256, prog, 2);
  prep_split_img<<<256, 256, 0, stream>>>(fcW, fcw, 1024, 1024, prog, 3);
  prep_uimg<<<256, 256, 0, stream>>>(Um, uim, prog);

  for (int c0 = 0; c0 < 128; c0 += tc){
    gemm_gates<<<dim3((2 * tc) * 32), 256, 0, stream>>>(emb, wim, bv, xgc, seq, c0, tcsh, prog);
    lstm_rec<<<dim3(64), 1024, 0, stream>>>(xgc, uim, len, hh, cb, ohol, barbase, prog, c0, tcsh);
    gemm_out<<<dim3((2 * tc) * 8), 256, 0, stream>>>(ohol, fcw, fcb, out, c0, tcsh, prog);
  }

  diag_check<<<1, 64, 0, stream>>>(prog, out);
}

// Round 5
// 4128.666 us; speedup vs baseline: 1.8829x; 1.8829x over previous
//
#include <hip/hip_runtime.h>

typedef short bf16x8 __attribute__((ext_vector_type(8)));   // 8 bf16 in 4 VGPRs
typedef float f32x4  __attribute__((ext_vector_type(4)));
typedef int   i32x4  __attribute__((ext_vector_type(4)));

#define DEVINL __device__ __forceinline__

// ---------------------------------------------------------------------------
// Problem: B=256, T=128, V=10000, E=256, U=1024, 4U=4096, O=1024
// fixed ws ~18.9 MB + tc*5.25 MB (tc=1 -> 24.1 MB floor)
// ---------------------------------------------------------------------------
static constexpr size_t SZ_WIM  = 4096ull * 512 * 2;   // W img  [4096][hi256|lo256]
static constexpr size_t SZ_FCW  = 1024ull * 2048 * 2;  // fc img [1024][hi1024|lo1024]
static constexpr size_t SZ_UIM  = 8388608;             // U i8 frag img, 2 planes
static constexpr size_t SZ_HB   = 1048576;             // [2 par][2 pl][256][1024] i8
static constexpr size_t SZ_CB   = 1048576;             // c state [256][1024] f32
static constexpr size_t SZ_LEN  = 4096;
static constexpr size_t SZ_DIAG = 512;                 // prog[0..31] + bar[mb] at 32+16*mb

DEVINL unsigned short bf16rn(float x){
  unsigned u = __float_as_uint(x);
  unsigned r = (u + 0x7fffu + ((u >> 16) & 1u)) >> 16;
  return (unsigned short)r;
}
DEVINL unsigned short bf16lo(float x){
  unsigned ub = __float_as_uint(x);
  return bf16rn(x - __uint_as_float(ub & 0xffff0000u));
}
DEVINL float sigm(float x){ return 1.f / (1.f + __expf(-x)); }
DEVINL float tanhfast(float x){
  float xc = fminf(15.f, fmaxf(-15.f, x));
  float e = __expf(2.f * xc);
  return (e - 1.f) / (e + 1.f);
}

// ---------------------------------------------------------------------------
__global__ void __launch_bounds__(256) probe_fill(float* __restrict__ out, int n, float v)
{
  int i = blockIdx.x * 256 + threadIdx.x;
  if (i < n) out[i] = (i == 0) ? v : 0.f;
}

// diag: if a stage marker is missing, flood out[0..1023] with 100+stage
__global__ void __launch_bounds__(64) diag_check(const int* __restrict__ prog,
                                                 float* __restrict__ out)
{
  if (threadIdx.x == 0){
    int miss = 0;
    for (int i = 7; i >= 1; i--) if (prog[i] == 0) miss = i;
    if (miss){
      for (int k = 0; k < 1024; k++) out[k] = 100.0f + (float)miss;
    }
  }
}

// ---------------------------------------------------------------------------
__global__ void __launch_bounds__(128) len_kernel(const int* __restrict__ seq,
                                                  int* __restrict__ len,
                                                  int* __restrict__ prog)
{
  int b = blockIdx.x, t = threadIdx.x;
  if (b == 0 && t == 0) prog[1] = 1;
  int pred = (seq[b * 128 + t] != 0) ? 1 : 0;
  unsigned long long m = __ballot(pred);
  __shared__ int cnt[2];
  if ((t & 63) == 0) cnt[t >> 6] = __popcll(m);
  __syncthreads();
  if (t == 0) len[b] = cnt[0] + cnt[1];
}

// ---------------------------------------------------------------------------
// transpose f32 [Ksrc][N] -> bf16 image [N][2*Ksrc] = [hi | lo]
// ---------------------------------------------------------------------------
__global__ void __launch_bounds__(256) prep_split_img(
    const float* __restrict__ S, unsigned short* __restrict__ img, int N, int Ksrc,
    int* __restrict__ prog, int stage)
{
  __shared__ float tile[64][65];
  const int nt = N >> 6;
  const int bn = blockIdx.x % nt, bk = blockIdx.x / nt;
  const int tid = threadIdx.x;
  if (blockIdx.x == 0 && tid == 0) prog[stage] = 1;
  {
    const int kk = tid >> 6, n = tid & 63;
#pragma unroll 4
    for (int i = 0; i < 16; i++){
      int k = i * 4 + kk;
      tile[k][n] = S[(size_t)((bk << 6) + k) * N + (bn << 6) + n];
    }
  }
  __syncthreads();
  {
    const int n4 = tid >> 6, k = tid & 63;
#pragma unroll 4
    for (int i = 0; i < 16; i++){
      int n = i * 4 + n4;
      float v = tile[k][n];
      size_t rowoff = (size_t)((bn << 6) + n) * (2 * Ksrc) + (bk << 6) + k;
      img[rowoff] = (unsigned short)(__float_as_uint(v) >> 16);
      img[rowoff + Ksrc] = bf16lo(v);
    }
  }
}

// ---------------------------------------------------------------------------
// U (f32 [1024][4096]) -> i8 fragment image, 2 planes (hi,lo of 16-bit *2^17)
// [nb 64][gate 4][kt 16][pl 2][lane 64][16B]; byte j = Uq(k=kt*64+quad*16+j,
// col=gate*1024+nb*16+(lane&15))
// ---------------------------------------------------------------------------
__global__ void __launch_bounds__(256) prep_uimg(const float* __restrict__ U,
                                                 signed char* __restrict__ img,
                                                 int* __restrict__ prog)
{
  const int bid = blockIdx.x;
  const int nb = bid >> 2, nt4 = bid & 3;
  const int tid = threadIdx.x;
  if (bid == 0 && tid == 0) prog[4] = 1;
  __shared__ signed char lc[16384], ldq[16384];  // [k 1024][16 cols]
  const int colbase = nt4 * 1024 + (nb << 4);
  const int kk = tid >> 4, cc = tid & 15;
#pragma unroll 4
  for (int it = 0; it < 64; it++){
    int k = it * 16 + kk;
    float v = U[(size_t)k * 4096 + colbase + cc];
    int q = (int)rintf(v * 131072.f);            // U * 2^17
    q = q > 32639 ? 32639 : (q < -32639 ? -32639 : q);
    int a = (q + 128) >> 8;
    int d = q - (a << 8);
    lc[(k << 4) + cc]  = (signed char)a;
    ldq[(k << 4) + cc] = (signed char)d;
  }
  __syncthreads();
#pragma unroll
  for (int rep = 0; rep < 4; rep++){
    int idx = rep * 256 + tid;                   // 0..1023
    int kt = idx >> 6, lane = idx & 63;
    int n = lane & 15, quad = lane >> 4;
    union { signed char b[16]; i32x4 v; } cb_, db_;
#pragma unroll
    for (int j = 0; j < 16; j++){
      int k = (kt << 6) + (quad << 4) + j;
      cb_.b[j] = lc[(k << 4) + n];
      db_.b[j] = ldq[(k << 4) + n];
    }
    size_t base = (size_t)((((nb << 2) + nt4) * 16 + kt) * 2) * 1024;
    *(i32x4*)(img + base + (size_t)lane * 16)        = cb_.v;
    *(i32x4*)(img + base + 1024 + (size_t)lane * 16) = db_.v;
  }
}

// ---------------------------------------------------------------------------
// gates GEMM: xg[256*tc][4096] = token-gathered emb x Wimg + bias (3-product).
// ---------------------------------------------------------------------------
__global__ void __launch_bounds__(256) gemm_gates(
    const float* __restrict__ emb, const unsigned short* __restrict__ Bimg,
    const float* __restrict__ bias, float* __restrict__ D,
    const int* __restrict__ seq, int c0, int tcsh, int* __restrict__ prog)
{
  __shared__ __align__(16) char lds[16384];   // A 8KB | B 8KB
  __shared__ int stok[128];
  const int tid = threadIdx.x, lane = tid & 63, wv = tid >> 6;
  const int quad = lane >> 4, nlo = lane & 15;
  const int wm = wv & 1, wn = wv >> 1;
  const int rowbase = (blockIdx.x >> 5) << 7;   // 32 col-tiles
  const int colbase = (blockIdx.x & 31) << 7;
  const int tcm1 = (1 << tcsh) - 1;
  if (blockIdx.x == 0 && tid == 0) prog[5] = 1;
  if (tid < 128){
    int r = rowbase + tid;
    stok[tid] = seq[((r >> tcsh) << 7) + c0 + (r & tcm1)];
  }
  __syncthreads();

  f32x4 acc[4][4];
#pragma unroll
  for (int i = 0; i < 4; i++)
#pragma unroll
    for (int j = 0; j < 4; j++) acc[i][j] = (f32x4){0.f, 0.f, 0.f, 0.f};

  float4 va[2][2]; int4 vb[2];
  auto loadAB = [&](int c){
    int k0 = c * 32;
    int seg = (k0 >= 512) ? 2 : (k0 >= 256 ? 1 : 0);
    int acol = k0 - seg * 256;
    int boff = (seg == 2 ? 256 : 0) + acol;
#pragma unroll
    for (int p = 0; p < 2; p++){
      int gidx = p * 256 + tid;
      int row = gidx >> 2, sg = gidx & 3;
      const float* ap = emb + (size_t)stok[row] * 256 + acol + sg * 8;
      va[p][0] = *(const float4*)ap;
      va[p][1] = *(const float4*)(ap + 4);
      vb[p] = *(const int4*)(Bimg + (size_t)(colbase + row) * 512 + boff + sg * 8);
    }
  };
  auto writeAB = [&](int c){
    int k0 = c * 32;
    int seg = (k0 >= 512) ? 2 : (k0 >= 256 ? 1 : 0);
#pragma unroll
    for (int p = 0; p < 2; p++){
      int gidx = p * 256 + tid;
      int row = gidx >> 2, sg = gidx & 3;
      float vv[8] = {va[p][0].x, va[p][0].y, va[p][0].z, va[p][0].w,
                     va[p][1].x, va[p][1].y, va[p][1].z, va[p][1].w};
      union { unsigned short s[8]; int4 q; } pk;
      if (seg == 1){
#pragma unroll
        for (int j = 0; j < 8; j++) pk.s[j] = bf16lo(vv[j]);
      } else {
#pragma unroll
        for (int j = 0; j < 8; j++) pk.s[j] = (unsigned short)(__float_as_uint(vv[j]) >> 16);
      }
      int sw = (sg ^ ((row >> 1) & 3)) << 4;
      *(int4*)(&lds[row * 64 + sw]) = pk.q;
      *(int4*)(&lds[8192 + row * 64 + sw]) = vb[p];
    }
  };

  loadAB(0);
#pragma unroll 2
  for (int c = 0; c < 24; c++){
    __syncthreads();
    writeAB(c);
    __syncthreads();
    if (c + 1 < 24) loadAB(c + 1);
    bf16x8 af[4], bfr[4];
#pragma unroll
    for (int mt = 0; mt < 4; mt++){
      int r = wm * 64 + mt * 16 + nlo;
      af[mt] = *(const bf16x8*)(&lds[r * 64 + ((quad ^ ((r >> 1) & 3)) << 4)]);
    }
#pragma unroll
    for (int nt = 0; nt < 4; nt++){
      int r = wn * 64 + nt * 16 + nlo;
      bfr[nt] = *(const bf16x8*)(&lds[8192 + r * 64 + ((quad ^ ((r >> 1) & 3)) << 4)]);
    }
#pragma unroll
    for (int mt = 0; mt < 4; mt++)
#pragma unroll
      for (int nt = 0; nt < 4; nt++)
        acc[mt][nt] = __builtin_amdgcn_mfma_f32_16x16x32_bf16(af[mt], bfr[nt], acc[mt][nt], 0, 0, 0);
  }

  float bs[4];
#pragma unroll
  for (int nt = 0; nt < 4; nt++) bs[nt] = bias[colbase + wn * 64 + nt * 16 + nlo];
#pragma unroll
  for (int mt = 0; mt < 4; mt++)
#pragma unroll
    for (int nt = 0; nt < 4; nt++){
      int col = colbase + wn * 64 + nt * 16 + nlo;
#pragma unroll
      for (int r = 0; r < 4; r++){
        int row = rowbase + wm * 64 + mt * 16 + quad * 4 + r;
        D[(size_t)row * 4096 + col] = acc[mt][nt][r] + bs[nt];
      }
    }
}

// ---------------------------------------------------------------------------
// output GEMM: out[b*128+c0+s][1024] = ohol x fcw + fcb (3-product, K'=3072)
// ---------------------------------------------------------------------------
__global__ void __launch_bounds__(256) gemm_out(
    const unsigned short* __restrict__ ohol, const unsigned short* __restrict__ Bimg,
    const float* __restrict__ bias, float* __restrict__ D,
    int c0, int tcsh, int* __restrict__ prog)
{
  __shared__ __align__(16) char lds[16384];
  const int tid = threadIdx.x, lane = tid & 63, wv = tid >> 6;
  const int quad = lane >> 4, nlo = lane & 15;
  const int wm = wv & 1, wn = wv >> 1;
  const int rowbase = (blockIdx.x >> 3) << 7;   // 8 col-tiles
  const int colbase = (blockIdx.x & 7) << 7;
  const int tcm1 = (1 << tcsh) - 1;
  if (blockIdx.x == 0 && tid == 0) prog[7] = 1;

  f32x4 acc[4][4];
#pragma unroll
  for (int i = 0; i < 4; i++)
#pragma unroll
    for (int j = 0; j < 4; j++) acc[i][j] = (f32x4){0.f, 0.f, 0.f, 0.f};

  int4 va[2], vb[2];
  auto loadAB = [&](int c){
    int k0 = c * 32;
    int seg = (k0 >= 2048) ? 2 : (k0 >= 1024 ? 1 : 0);
    int acol = k0 - seg * 1024;
    int aoff = (seg == 1 ? 1024 : 0) + acol;
    int boff = (seg == 2 ? 1024 : 0) + acol;
#pragma unroll
    for (int p = 0; p < 2; p++){
      int gidx = p * 256 + tid;
      int row = gidx >> 2, sg = gidx & 3;
      va[p] = *(const int4*)(ohol + (size_t)(rowbase + row) * 2048 + aoff + sg * 8);
      vb[p] = *(const int4*)(Bimg + (size_t)(colbase + row) * 2048 + boff + sg * 8);
    }
  };
  auto writeAB = [&](){
#pragma unroll
    for (int p = 0; p < 2; p++){
      int gidx = p * 256 + tid;
      int row = gidx >> 2, sg = gidx & 3;
      int sw = (sg ^ ((row >> 1) & 3)) << 4;
      *(int4*)(&lds[row * 64 + sw]) = va[p];
      *(int4*)(&lds[8192 + row * 64 + sw]) = vb[p];
    }
  };

  loadAB(0);
#pragma unroll 2
  for (int c = 0; c < 96; c++){
    __syncthreads();
    writeAB();
    __syncthreads();
    if (c + 1 < 96) loadAB(c + 1);
    bf16x8 af[4], bfr[4];
#pragma unroll
    for (int mt = 0; mt < 4; mt++){
      int r = wm * 64 + mt * 16 + nlo;
      af[mt] = *(const bf16x8*)(&lds[r * 64 + ((quad ^ ((r >> 1) & 3)) << 4)]);
    }
#pragma unroll
    for (int nt = 0; nt < 4; nt++){
      int r = wn * 64 + nt * 16 + nlo;
      bfr[nt] = *(const bf16x8*)(&lds[8192 + r * 64 + ((quad ^ ((r >> 1) & 3)) << 4)]);
    }
#pragma unroll
    for (int mt = 0; mt < 4; mt++)
#pragma unroll
      for (int nt = 0; nt < 4; nt++)
        acc[mt][nt] = __builtin_amdgcn_mfma_f32_16x16x32_bf16(af[mt], bfr[nt], acc[mt][nt], 0, 0, 0);
  }

  float bs[4];
#pragma unroll
  for (int nt = 0; nt < 4; nt++) bs[nt] = bias[colbase + wn * 64 + nt * 16 + nlo];
#pragma unroll
  for (int mt = 0; mt < 4; mt++)
#pragma unroll
    for (int nt = 0; nt < 4; nt++){
      int col = colbase + wn * 64 + nt * 16 + nlo;
#pragma unroll
      for (int r = 0; r < 4; r++){
        int row = rowbase + wm * 64 + mt * 16 + quad * 4 + r;
        int drow = ((row >> tcsh) << 7) + c0 + (row & tcm1);
        D[(size_t)drow * 1024 + col] = acc[mt][nt][r] + bs[nt];
      }
    }
}

// ---------------------------------------------------------------------------
// per-mb-group barrier (64 WGs), monotonic counter — exact round-1 protocol
// (fastest measured + proven correct):
//   - h stores are sc1 write-through relaxed atomics.
//   - arrival: RELAXED agent fetch_add; spin RELAXED (no per-poll cache ops).
//   - ONE acquire agent fence (L1+L2 inv) per WG per step after the spin.
// ---------------------------------------------------------------------------
DEVINL void mbbar(int* bar, int t, int tid){
  __syncthreads();   // implies s_waitcnt vmcnt(0): sc1 h-stores are globally visible
  if (tid == 0){
    __hip_atomic_fetch_add(bar, 1, __ATOMIC_RELAXED, __HIP_MEMORY_SCOPE_AGENT);
    const int target = 64 * (t + 1);
    while (__hip_atomic_load(bar, __ATOMIC_RELAXED, __HIP_MEMORY_SCOPE_AGENT) < target)
      __builtin_amdgcn_s_sleep(1);
    __builtin_amdgcn_fence(__ATOMIC_ACQUIRE, "agent");  // single L1+L2 inv
  }
  __syncthreads();
}

// ---------------------------------------------------------------------------
// persistent LSTM recurrence, tc steps/launch.  256 WGs x 512 thr = 4 mb x 64 nb.
// Round-5 change vs round 1 (same geometry, protocol, arithmetic):
//   - 8 waves/WG = mh(2) x gate(4): per-lane U-frags Bf[16][2] = 128 VGPRs
//     (was 256 across [2 gates][16 kt][2 pl] -> didn't fit, runtime-indexed,
//     compiler spilled to SCRATCH: every MFMA B-operand was a buffer_load.
//     Evidence: FETCH_SIZE ~1.3GB invariant across R1/R3/R4; VGPR_Count 64).
//   - c-loop FULLY UNROLLED so Bf indices are compile-time (rule #20).
// h,U 2-plane i8 fixed point (h*32512 = 256a+d; U*2^17 = 256c+e); exact i32.
// ---------------------------------------------------------------------------
__global__ void __launch_bounds__(512, 2) lstm_rec(
    const float* __restrict__ xg,        // [256*tc][4096] f32, row = b*tc+s
    const signed char* __restrict__ uimg,
    const int* __restrict__ len,
    signed char* __restrict__ hb,        // [2 par][2 pl][256][1024] i8
    float* __restrict__ cbuf,            // [256][1024] f32
    unsigned short* __restrict__ ohol,   // [256*tc][hi1024|lo1024]
    int* __restrict__ barbase,           // bar[mb] at barbase + mb*16
    int* __restrict__ prog,
    int c0, int tcsh)
{
  // LDS: [0,16384) h tile (2 pl x 64 r x 128B); [16384,32768) xg f32 [64][64];
  //      [32768,50176) z f32 [64][68]
  __shared__ __align__(16) char lds[50176];
  const int tc = 1 << tcsh;
  const int wg = blockIdx.x, mb = wg >> 6, nb = wg & 63;
  const int tid = threadIdx.x, lane = tid & 63, wv = tid >> 6;  // wv 0..7
  const int quad = lane >> 4, nlo = lane & 15;
  const int mh = wv & 1, g = wv >> 1;                           // gate 0..3
  int* bar = barbase + (mb << 4);
  if (wg == 0 && tid == 0) prog[6] = 1;

  // ---- U fragments -> registers: gate g, u-block nb, 16 kt x 2 planes ----
  i32x4 Bf[16][2];
#pragma unroll
  for (int kt = 0; kt < 16; kt++)
#pragma unroll
    for (int pl = 0; pl < 2; pl++){
      size_t off = (size_t)((((nb << 2) + g) * 16 + kt) * 2 + pl);
      off = (off * 64 + lane) << 4;
      Bf[kt][pl] = *(const i32x4*)(uimg + off);
    }

  const int uu = tid & 15, qq = tid >> 4;        // qq 0..31
  const int ucol = (nb << 4) + uu;
  float cst[2], hst[2];
  int lenr[2];
#pragma unroll
  for (int r = 0; r < 2; r++){
    int bglob = (mb << 6) + (qq << 1) + r;
    lenr[r] = len[bglob];
    cst[r] = cbuf[(size_t)bglob * 1024 + ucol];
    int a  = hb[((size_t)((c0 & 1) * 2 + 0) * 256 + bglob) * 1024 + ucol];
    int b_ = hb[((size_t)((c0 & 1) * 2 + 1) * 256 + bglob) * 1024 + ucol];
    hst[r] = (float)(a * 256 + b_) * (1.0f / 32512.0f);
  }

  // xg prefetch: issued before mbbar so HBM latency hides under the spin.
  float4 xreg[2];
  auto load_x = [&](int s){
#pragma unroll
    for (int it = 0; it < 2; it++){
      int idx = it * 512 + tid;
      int row = idx >> 4, c4 = idx & 15;
      xreg[it] = *(const float4*)(xg + (size_t)((((mb << 6) + row) << tcsh) + s) * 4096
                                  + (c4 >> 2) * 1024 + (nb << 4) + ((c4 & 3) << 2));
    }
  };
  load_x(0);

#pragma unroll 1
  for (int s = 0; s < tc; s++){
    const int t = c0 + s;
    const int par = t & 1, par2 = par ^ 1;
    const signed char* hsrc = hb + ((size_t)par * 512 + (size_t)(mb << 6)) * 1024;

    i32x4 accH[2], accM[2], accL[2];
#pragma unroll
    for (int m = 0; m < 2; m++){
      accH[m] = (i32x4){0,0,0,0};
      accM[m] = (i32x4){0,0,0,0};
      accL[m] = (i32x4){0,0,0,0};
    }

    int4 hreg[2];
    auto load_h = [&](int c){
#pragma unroll
      for (int it = 0; it < 2; it++){
        int idx = it * 512 + tid;
        int hg = idx & 7, hr = (idx >> 3) & 63, hpl = idx >> 9;
        hreg[it] = *(const int4*)(hsrc + ((size_t)(hpl * 256 + hr)) * 1024 + c * 128 + hg * 16);
      }
    };
    auto write_h = [&](){
#pragma unroll
      for (int it = 0; it < 2; it++){
        int idx = it * 512 + tid;
        int hg = idx & 7, hr = (idx >> 3) & 63, hpl = idx >> 9;
        *(int4*)(&lds[hpl * 8192 + hr * 128 + ((hg ^ (hr & 7)) << 4)]) = hreg[it];
      }
    };

    load_h(0);

#pragma unroll                         // FULL unroll: Bf[kt] compile-time
    for (int c = 0; c < 8; c++){
      __syncthreads();
      write_h();
      if (c == 0){
#pragma unroll
        for (int it = 0; it < 2; it++){
          int idx = it * 512 + tid;
          int row = idx >> 4, c4 = idx & 15;
          *(float4*)(&lds[16384 + row * 256 + c4 * 16]) = xreg[it];
        }
      }
      __syncthreads();
      if (c < 7) load_h(c + 1);
#pragma unroll
      for (int kt2 = 0; kt2 < 2; kt2++){
        const int kt = c * 2 + kt2;
        i32x4 Af[2][2];
#pragma unroll
        for (int m = 0; m < 2; m++)
#pragma unroll
          for (int pl = 0; pl < 2; pl++){
            int hrow = (mh << 5) + (m << 4) + nlo;
            int sgl = ((kt2 << 2) + quad) ^ (hrow & 7);
            Af[m][pl] = *(const i32x4*)(&lds[pl * 8192 + hrow * 128 + (sgl << 4)]);
          }
#pragma unroll
        for (int m = 0; m < 2; m++){
          accH[m] = __builtin_amdgcn_mfma_i32_16x16x64_i8(Af[m][0], Bf[kt][0], accH[m], 0, 0, 0);
          accM[m] = __builtin_amdgcn_mfma_i32_16x16x64_i8(Af[m][0], Bf[kt][1], accM[m], 0, 0, 0);
          accM[m] = __builtin_amdgcn_mfma_i32_16x16x64_i8(Af[m][1], Bf[kt][0], accM[m], 0, 0, 0);
          accL[m] = __builtin_amdgcn_mfma_i32_16x16x64_i8(Af[m][1], Bf[kt][1], accL[m], 0, 0, 0);
        }
      }
    }
    __syncthreads();

    // prefetch next step's xg under the z/elementwise/barrier phases
    if (s + 1 < tc) load_x(s + 1);

    // ---- z = (65536*accH + 256*accM + accL)/(32512*2^17) -> LDS ----
    const float cH = 1.0f / 65024.0f;
    const float cM = 1.0f / 16646144.0f;
    const float cL = 1.0f / 4261412864.0f;
#pragma unroll
    for (int m = 0; m < 2; m++){
#pragma unroll
      for (int r = 0; r < 4; r++){
        float z = (float)accH[m][r] * cH
                + (float)accM[m][r] * cM
                + (float)accL[m][r] * cL;
        int zrow = (mh << 5) + (m << 4) + (quad << 2) + r;
        *(float*)(&lds[32768 + (((zrow * 68) + g * 16 + nlo) << 2)]) = z;
      }
    }
    __syncthreads();

#pragma unroll
    for (int r = 0; r < 2; r++){
      int zrow = (qq << 1) + r;
      int bglob = (mb << 6) + zrow;
      float zi = *(const float*)(&lds[32768 + (((zrow * 68) + 0  + uu) << 2)])
               + *(const float*)(&lds[16384 + (((zrow << 6) + 0  + uu) << 2)]);
      float zf = *(const float*)(&lds[32768 + (((zrow * 68) + 16 + uu) << 2)])
               + *(const float*)(&lds[16384 + (((zrow << 6) + 16 + uu) << 2)]);
      float zg = *(const float*)(&lds[32768 + (((zrow * 68) + 32 + uu) << 2)])
               + *(const float*)(&lds[16384 + (((zrow << 6) + 32 + uu) << 2)]);
      float zo = *(const float*)(&lds[32768 + (((zrow * 68) + 48 + uu) << 2)])
               + *(const float*)(&lds[16384 + (((zrow << 6) + 48 + uu) << 2)]);
      float iv = sigm(zi), fv = sigm(zf), ov = sigm(zo), gv = tanhfast(zg);
      float cn = fv * cst[r] + iv * gv;
      float hn = ov * tanhfast(cn);
      bool vld = (t < lenr[r]);
      cst[r] = vld ? cn : cst[r];
      hst[r] = vld ? hn : hst[r];
      float ho = vld ? hn : 0.f;
      size_t orow = ((size_t)bglob << tcsh) + s;
      ohol[orow * 2048 + ucol]        = (unsigned short)(__float_as_uint(ho) >> 16);
      ohol[orow * 2048 + 1024 + ucol] = bf16lo(ho);
      int H = (int)rintf(hst[r] * 32512.f);
      H = H > 32512 ? 32512 : (H < -32512 ? -32512 : H);
      int a = (H + 128) >> 8;
      int b_ = H - (a << 8);
      // sc1 write-through: visible agent-wide once vmcnt-complete; reader-side
      // acquire fence in mbbar makes the remote read safe (round-1 protocol).
      __hip_atomic_store(&hb[((size_t)(par2 * 2 + 0) * 256 + bglob) * 1024 + ucol],
                         (signed char)a, __ATOMIC_RELAXED, __HIP_MEMORY_SCOPE_AGENT);
      __hip_atomic_store(&hb[((size_t)(par2 * 2 + 1) * 256 + bglob) * 1024 + ucol],
                         (signed char)b_, __ATOMIC_RELAXED, __HIP_MEMORY_SCOPE_AGENT);
    }
    mbbar(bar, t, tid);
  }

#pragma unroll
  for (int r = 0; r < 2; r++){
    int bglob = (mb << 6) + (qq << 1) + r;
    cbuf[(size_t)bglob * 1024 + ucol] = cst[r];
  }
}

// ---------------------------------------------------------------------------
extern "C" void kernel_launch(void* const* d_in, const int* in_sizes, int n_in,
                              void* d_out, int out_size, void* d_ws, size_t ws_size,
                              hipStream_t stream)
{
  const int*   seq = (const int*)  d_in[0];
  const float* emb = (const float*)d_in[1];
  const float* Wm  = (const float*)d_in[2];
  const float* Um  = (const float*)d_in[3];
  const float* bv  = (const float*)d_in[4];
  const float* fcW = (const float*)d_in[5];
  const float* fcb = (const float*)d_in[6];
  float* out = (float*)d_out;
  char* ws = (char*)d_ws;

  // marker: survives iff no kernel/memset below ever touches d_out
  hipMemsetAsync(d_out, 0x42, 256, stream);   // 64 floats = 48.566

  size_t off = 0;
  unsigned short* wim = (unsigned short*)(ws + off); off += SZ_WIM;
  unsigned short* fcw = (unsigned short*)(ws + off); off += SZ_FCW;
  signed char*    uim = (signed char*)(ws + off);    off += SZ_UIM;
  signed char*    hb  = (signed char*)(ws + off);    off += SZ_HB;
  float*          cb  = (float*)(ws + off);          off += SZ_CB;
  int*            len = (int*)(ws + off);            off += SZ_LEN;
  int*            diag= (int*)(ws + off);            off += SZ_DIAG;
  const size_t fixed = off;

  int tcsh = -1;
  for (int s = 5; s >= 0; s--)
    if (ws && fixed + (5242880ull << s) <= ws_size){ tcsh = s; break; }

  if (tcsh < 0){
    probe_fill<<<(out_size + 255) / 256, 256, 0, stream>>>(
        out, out_size, 1000.0f + (float)(ws_size >> 20));
    return;
  }
  const int tc = 1 << tcsh;

  float*          xgc  = (float*)(ws + fixed);
  unsigned short* ohol = (unsigned short*)(ws + fixed + (size_t)tc * 4194304);

  hipMemsetAsync(diag, 0, SZ_DIAG, stream);   // prog + per-mb barrier counters
  hipMemsetAsync(hb, 0, 524288, stream);      // parity-0 h planes = 0
  hipMemsetAsync(cb, 0, SZ_CB, stream);       // c state = 0

  int* prog = diag;
  int* barbase = diag + 32;

  len_kernel<<<256, 128, 0, stream>>>(seq, len, prog);
  prep_split_img<<<256, 256, 0, stream>>>(Wm, wim, 4096, 256, prog, 2);
  prep_split_img<<<256, 256, 0, stream>>>(fcW, fcw, 1024, 1024, prog, 3);
  prep_uimg<<<256, 256, 0, stream>>>(Um, uim, prog);

  for (int c0 = 0; c0 < 128; c0 += tc){
    gemm_gates<<<dim3((2 * tc) * 32), 256, 0, stream>>>(emb, wim, bv, xgc, seq, c0, tcsh, prog);
    lstm_rec<<<dim3(256), 512, 0, stream>>>(xgc, uim, len, hb, cb, ohol, barbase, prog, c0, tcsh);
    gemm_out<<<dim3((2 * tc) * 8), 256, 0, stream>>>(ohol, fcw, fcb, out, c0, tcsh, prog);
  }

  diag_check<<<1, 64, 0, stream>>>(prog, out);
}